// Round 16
// baseline (592.226 us; speedup 1.0000x reference)
//
#include <hip/hip_runtime.h>

typedef float f32x4 __attribute__((ext_vector_type(4)));

#define TSTEPS 500
#define BDIM 64
#define CIN 512
#define COUT 512
#define MTOT (TSTEPS * BDIM)   // 32000
#define NCH (BDIM * CIN)       // 32768
#define SNEUR (BDIM * COUT)    // 32768
#define OUTN ((size_t)TSTEPS * SNEUR + SNEUR)

#define AL64 0.95122942450071400909   // math.exp(-0.001/0.02), f64
#define BL64 (1.0 - AL64)

__global__ __launch_bounds__(256) void fill_const_f32(
    float* __restrict__ p, size_t n, float c) {
  size_t i = (size_t)blockIdx.x * 256 + threadIdx.x;
  const size_t stride = (size_t)gridDim.x * 256;
  for (; i < n; i += stride) p[i] = c;
}

__device__ __forceinline__ void gll16(const float* g, float* l) {
  __builtin_amdgcn_global_load_lds(
      (const __attribute__((address_space(1))) void*)g,
      (__attribute__((address_space(3))) void*)l, 16, 0, 0);
}

// ---------------------------------------------------------------------------
// f32 trace scan (np-exact): tr = fl(fl(a*tr) + x)   [proven R13]
// ---------------------------------------------------------------------------
__global__ __launch_bounds__(256) void trace32(
    const float* __restrict__ X, float* __restrict__ TR,
    const float* __restrict__ alpha) {
  const int j = blockIdx.x * 256 + threadIdx.x;  // b*512 + ci
  const float a = fminf(fmaxf(alpha[0], 0.0f), 0.9999f);
  float tr = 0.0f;
#pragma unroll 10
  for (int t = 0; t < TSTEPS; ++t) {
    float x = X[(size_t)t * NCH + j];
    tr = __fadd_rn(__fmul_rn(a, tr), x);
    TR[(size_t)t * NCH + j] = tr;
  }
}

// ---------------------------------------------------------------------------
// Fused CUR = (X@W) + (TR@W); reduction order IDENTICAL to R13/R14/R15
// (head chain k<384, tail chain k>=384, combine fadd(fadd(xH,xT),fadd(tH,tT))).
// Geometry = R14 (BM=64 x BN=128, 4x8/thread, 128 accs) but WITHOUT the
// launch_bounds min-waves cap that forced R14's 128-VGPR spill; compiler is
// free to take ~185 VGPRs at 2 waves/SIMD. Staging = R14/R15 proven:
// double-buffered global_load_lds(16B), A k-group XOR pre-swizzle on the
// global source (rule #21), un-swizzle on read (bank conflicts = 0).
// Grid = 2000 1-D blocks with XCD-chunked swizzle (T1): the 4 bn-blocks
// sharing one A row-panel run on the same XCD -> L2 reuse.
// ---------------------------------------------------------------------------
__global__ __launch_bounds__(256) void gemm_fused4(
    const float* __restrict__ X, const float* __restrict__ TR,
    const float* __restrict__ W, float* __restrict__ CUR) {
  __shared__ __align__(16) float Ax[2][1024];  // [buf][64 rows x 16 k]
  __shared__ __align__(16) float At[2][1024];
  __shared__ __align__(16) float Bs[2][2048];  // [buf][16 k x 128 n]
  const int tid = threadIdx.x;
  const int ty = tid >> 4, tx = tid & 15;

  // XCD-chunked bijective swizzle: nwg=2000, 8 XCDs, 250 blocks per XCD.
  const int fid = blockIdx.x;
  const int swz = (fid & 7) * 250 + (fid >> 3);
  const int bm = (swz >> 2) * 64;        // 500 row-panels
  const int bn = (swz & 3) * 128;        // 4 col-panels (bn fastest in swz)

  const int wb = (tid & 192) * 4;  // wave-uniform LDS float offset

  // staging sources (per-lane 16B); A source pre-swizzled by k-group
  const int arow = tid >> 2, ag = tid & 3;
  const int ags = ag ^ ((arow >> 2) & 3);
  const float* sx = X + (size_t)(bm + arow) * CIN + ags * 4;
  const float* st = TR + (size_t)(bm + arow) * CIN + ags * 4;
  const int brow0 = tid >> 5, bcg = (tid & 31) * 4;
  const float* sb0 = W + (size_t)brow0 * COUT + bn + bcg;        // k 0..7
  const float* sb1 = W + (size_t)(8 + brow0) * COUT + bn + bcg;  // k 8..15

  float xH[4][8] = {{0.0f}}, xT[4][8] = {{0.0f}};
  float tH[4][8] = {{0.0f}}, tT[4][8] = {{0.0f}};

  auto stage = [&](int b) {
    gll16(sx, &Ax[b][wb]);
    gll16(st, &At[b][wb]);
    gll16(sb0, &Bs[b][wb]);
    gll16(sb1, &Bs[b][1024 + wb]);
    sx += 16; st += 16;                  // next 16 k
    sb0 += 16 * COUT; sb1 += 16 * COUT;  // next 16 k rows
  };

  const int sw = ty & 3;  // A read-side un-swizzle ((row>>2)&3 == ty&3)

#define COMPUTE(b, AX, AT)                                                   \
  {                                                                          \
    const float* axp = Ax[b];                                                \
    const float* atp = At[b];                                                \
    const float* bsp = Bs[b];                                                \
    _Pragma("unroll") for (int kg = 0; kg < 4; ++kg) {                       \
      const int G = (kg ^ sw) * 4;                                           \
      f32x4 avx[4], avt[4];                                                  \
      _Pragma("unroll") for (int i = 0; i < 4; ++i) {                        \
        avx[i] = *(const f32x4*)&axp[(ty * 4 + i) * 16 + G];                 \
        avt[i] = *(const f32x4*)&atp[(ty * 4 + i) * 16 + G];                 \
      }                                                                      \
      _Pragma("unroll") for (int k2 = 0; k2 < 4; ++k2) {                     \
        f32x4 bL = *(const f32x4*)&bsp[(kg * 4 + k2) * 128 + tx * 4];        \
        f32x4 bH = *(const f32x4*)&bsp[(kg * 4 + k2) * 128 + 64 + tx * 4];   \
        _Pragma("unroll") for (int i = 0; i < 4; ++i)                        \
          _Pragma("unroll") for (int j = 0; j < 4; ++j) {                    \
            AX[i][j]     = fmaf(avx[i][k2], bL[j], AX[i][j]);                \
            AX[i][4 + j] = fmaf(avx[i][k2], bH[j], AX[i][4 + j]);            \
            AT[i][j]     = fmaf(avt[i][k2], bL[j], AT[i][j]);                \
            AT[i][4 + j] = fmaf(avt[i][k2], bH[j], AT[i][4 + j]);            \
          }                                                                  \
      }                                                                      \
    }                                                                        \
  }

  stage(0);
  int buf = 0;
  for (int kt = 0; kt < 32; ++kt) {
    __syncthreads();               // drains vmcnt -> buf[buf] staged
    if (kt < 31) stage(buf ^ 1);   // async prefetch next tile during compute
    if (kt < 24) {
      COMPUTE(buf, xH, tH);        // head: k in [0,384)
    } else {
      COMPUTE(buf, xT, tT);        // tail: k in [384,512)
    }
    buf ^= 1;
  }
#undef COMPUTE

#pragma unroll
  for (int i = 0; i < 4; ++i) {
    const size_t row = (size_t)(bm + ty * 4 + i);
    f32x4 L, H;
#pragma unroll
    for (int j = 0; j < 4; ++j) {
      L[j] = __fadd_rn(__fadd_rn(xH[i][j], xT[i][j]),
                       __fadd_rn(tH[i][j], tT[i][j]));
      H[j] = __fadd_rn(__fadd_rn(xH[i][4 + j], xT[i][4 + j]),
                       __fadd_rn(tH[i][4 + j], tT[i][4 + j]));
    }
    *(f32x4*)&CUR[row * COUT + bn + tx * 4] = L;
    *(f32x4*)&CUR[row * COUT + bn + 64 + tx * 4] = H;
  }
}

// ---------------------------------------------------------------------------
// f32 LIF chain (np-exact): v = fl(fl(AL*v)+fl(BL*cur)); s=(v-1>0); reset.
// spikes {0,1}; rates = count/500.   [proven R13]
// ---------------------------------------------------------------------------
__global__ __launch_bounds__(256) void lif32(
    const float* __restrict__ CUR, float* __restrict__ spikes,
    float* __restrict__ rates) {
  const int j = blockIdx.x * 256 + threadIdx.x;  // b*512 + n
  const float AL = (float)AL64, BL = (float)BL64;
  float v = 0.0f;
  int cnt = 0;
#pragma unroll 10
  for (int t = 0; t < TSTEPS; ++t) {
    float cur = CUR[(size_t)t * SNEUR + j];
    v = __fadd_rn(__fmul_rn(AL, v), __fmul_rn(BL, cur));
    int sp = __fadd_rn(v, -1.0f) > 0.0f;
    cnt += sp;
    spikes[(size_t)t * SNEUR + j] = sp ? 1.0f : 0.0f;
    v = sp ? 0.0f : v;
  }
  rates[j] = __fdiv_rn((float)cnt, 500.0f);
}

extern "C" void kernel_launch(void* const* d_in, const int* in_sizes, int n_in,
                              void* d_out, int out_size, void* d_ws, size_t ws_size,
                              hipStream_t stream) {
  float* out = (float*)d_out;  // f32: spikes [500*64*512] ++ rates [64*512]

  float flag = 0.0f;
  const float* X = nullptr;
  const float* W = nullptr;
  const float* AP = nullptr;
  if (n_in != 3) {
    flag = 11.0f;
  } else {
    for (int i = 0; i < 3; ++i) {
      if (in_sizes[i] == 16384000) X = (const float*)d_in[i];
      else if (in_sizes[i] == 262144) W = (const float*)d_in[i];
      else if (in_sizes[i] == 1) AP = (const float*)d_in[i];
    }
    if (!X || !W || !AP) flag = 13.0f;
    else if (out_size != (int)OUTN) flag = 17.0f;
    else if (ws_size < 2ull * MTOT * CIN * 4ull) flag = 23.0f;
  }
  if (flag != 0.0f) {
    fill_const_f32<<<dim3(2048), dim3(256), 0, stream>>>(out, OUTN, flag);
    return;
  }

  float* TR = (float*)d_ws;                 // trace [32000,512] f32
  float* CUR = TR + (size_t)MTOT * CIN;     // current [32000,512] f32

  trace32<<<dim3(NCH / 256), dim3(256), 0, stream>>>(X, TR, AP);
  gemm_fused4<<<dim3(2000), dim3(256), 0, stream>>>(X, TR, W, CUR);
  lif32<<<dim3(SNEUR / 256), dim3(256), 0, stream>>>(
      CUR, out, out + (size_t)TSTEPS * SNEUR);
}

// Round 17
// 502.637 us; speedup vs baseline: 1.1782x; 1.1782x over previous
//
#include <hip/hip_runtime.h>

typedef float f32x4 __attribute__((ext_vector_type(4)));

#define TSTEPS 500
#define BDIM 64
#define CIN 512
#define COUT 512
#define MTOT (TSTEPS * BDIM)   // 32000
#define NCH (BDIM * CIN)       // 32768
#define SNEUR (BDIM * COUT)    // 32768
#define OUTN ((size_t)TSTEPS * SNEUR + SNEUR)

#define AL64 0.95122942450071400909   // math.exp(-0.001/0.02), f64
#define BL64 (1.0 - AL64)

#define BUF_BYTES 65536000ull  // one [32000,512] f32 plane
#define WS_NEED (3ull * BUF_BYTES)

__global__ __launch_bounds__(256) void fill_const_f32(
    float* __restrict__ p, size_t n, float c) {
  size_t i = (size_t)blockIdx.x * 256 + threadIdx.x;
  const size_t stride = (size_t)gridDim.x * 256;
  for (; i < n; i += stride) p[i] = c;
}

// ---------------------------------------------------------------------------
// f32 trace scan (np-exact): tr = fl(fl(a*tr) + x)   [proven R13]
// ---------------------------------------------------------------------------
__global__ __launch_bounds__(256) void trace32(
    const float* __restrict__ X, float* __restrict__ TR,
    const float* __restrict__ alpha) {
  const int j = blockIdx.x * 256 + threadIdx.x;  // b*512 + ci
  const float a = fminf(fmaxf(alpha[0], 0.0f), 0.9999f);
  float tr = 0.0f;
#pragma unroll 10
  for (int t = 0; t < TSTEPS; ++t) {
    float x = X[(size_t)t * NCH + j];
    tr = __fadd_rn(__fmul_rn(a, tr), x);
    TR[(size_t)t * NCH + j] = tr;
  }
}

// ---------------------------------------------------------------------------
// Head/tail split GEMM pair. Reduction order bit-identical to R13 (proven):
// per output, each chain (x / trace) is an ascending-k f32 FMA chain split
// at k=384 (BLAS KC); combine = fadd(fadd(xH,xT), fadd(tH,tT)).
// Geometry: BM=64 x BN=128, 256 thr, 4x8/thread, TWO chain-sets per kernel
// (64 accs) so fragments keep register room (R16 lesson). R13-style direct
// staging (beat gll-dbuf 470 vs 518), padded LDS (2-way = free), XCD-chunked
// block swizzle (R16-proven: FETCH 519->84 MB).
// ---------------------------------------------------------------------------
#define GEMM_SHARED                                  \
  __shared__ __align__(16) float Asx[64][20];        \
  __shared__ __align__(16) float Ast[64][20];        \
  __shared__ __align__(16) float Bs[16][132];

#define GEMM_SETUP                                   \
  const int tid = threadIdx.x;                       \
  const int ty = tid >> 4, tx = tid & 15;            \
  const int fid = blockIdx.x;                        \
  const int swz = (fid & 7) * 250 + (fid >> 3);      \
  const int bm = (swz >> 2) * 64;                    \
  const int bn = (swz & 3) * 128;                    \
  const int ar = tid >> 2, ak = (tid & 3) * 4;       \
  const int bk = tid >> 4, bc = (tid & 15) * 8;

#define GEMM_STEP(kt)                                                        \
  {                                                                          \
    *(f32x4*)&Asx[ar][ak] =                                                  \
        *(const f32x4*)&X[(size_t)(bm + ar) * CIN + (kt)*16 + ak];           \
    *(f32x4*)&Ast[ar][ak] =                                                  \
        *(const f32x4*)&TR[(size_t)(bm + ar) * CIN + (kt)*16 + ak];          \
    *(f32x4*)&Bs[bk][bc] =                                                   \
        *(const f32x4*)&W[(size_t)((kt)*16 + bk) * COUT + bn + bc];          \
    *(f32x4*)&Bs[bk][bc + 4] =                                               \
        *(const f32x4*)&W[(size_t)((kt)*16 + bk) * COUT + bn + bc + 4];      \
    __syncthreads();                                                         \
    _Pragma("unroll") for (int kg = 0; kg < 4; ++kg) {                       \
      f32x4 ax[4], at4[4];                                                   \
      _Pragma("unroll") for (int i = 0; i < 4; ++i) {                        \
        ax[i] = *(const f32x4*)&Asx[ty * 4 + i][kg * 4];                     \
        at4[i] = *(const f32x4*)&Ast[ty * 4 + i][kg * 4];                    \
      }                                                                      \
      _Pragma("unroll") for (int k2 = 0; k2 < 4; ++k2) {                     \
        f32x4 bL = *(const f32x4*)&Bs[kg * 4 + k2][tx * 4];                  \
        f32x4 bH = *(const f32x4*)&Bs[kg * 4 + k2][64 + tx * 4];             \
        _Pragma("unroll") for (int i = 0; i < 4; ++i)                        \
          _Pragma("unroll") for (int j = 0; j < 4; ++j) {                    \
            xA[i][j]     = fmaf(ax[i][k2], bL[j], xA[i][j]);                 \
            xA[i][4 + j] = fmaf(ax[i][k2], bH[j], xA[i][4 + j]);             \
            tA[i][j]     = fmaf(at4[i][k2], bL[j], tA[i][j]);                \
            tA[i][4 + j] = fmaf(at4[i][k2], bH[j], tA[i][4 + j]);            \
          }                                                                  \
      }                                                                      \
    }                                                                        \
    __syncthreads();                                                         \
  }

__global__ __launch_bounds__(256) void gemm_head(
    const float* __restrict__ X, const float* __restrict__ TR,
    const float* __restrict__ W, float* __restrict__ PHx,
    float* __restrict__ PHt) {
  GEMM_SHARED
  GEMM_SETUP
  float xA[4][8] = {{0.0f}}, tA[4][8] = {{0.0f}};
  for (int kt = 0; kt < 24; ++kt) GEMM_STEP(kt)   // head: k in [0,384)

#pragma unroll
  for (int i = 0; i < 4; ++i) {
    const size_t row = (size_t)(bm + ty * 4 + i);
    f32x4 xL, xH2, tL, tH2;
#pragma unroll
    for (int j = 0; j < 4; ++j) {
      xL[j] = xA[i][j];   xH2[j] = xA[i][4 + j];
      tL[j] = tA[i][j];   tH2[j] = tA[i][4 + j];
    }
    *(f32x4*)&PHx[row * COUT + bn + tx * 4] = xL;
    *(f32x4*)&PHx[row * COUT + bn + 64 + tx * 4] = xH2;
    *(f32x4*)&PHt[row * COUT + bn + tx * 4] = tL;
    *(f32x4*)&PHt[row * COUT + bn + 64 + tx * 4] = tH2;
  }
}

__global__ __launch_bounds__(256) void gemm_tail(
    const float* __restrict__ X, const float* __restrict__ TR,
    const float* __restrict__ W, float* __restrict__ PHx,   // becomes CUR
    const float* __restrict__ PHt) {
  GEMM_SHARED
  GEMM_SETUP
  float xA[4][8] = {{0.0f}}, tA[4][8] = {{0.0f}};
  for (int kt = 24; kt < 32; ++kt) GEMM_STEP(kt)  // tail: k in [384,512)

#pragma unroll
  for (int i = 0; i < 4; ++i) {
    const size_t row = (size_t)(bm + ty * 4 + i);
    const size_t iL = row * COUT + bn + tx * 4;
    const size_t iH = row * COUT + bn + 64 + tx * 4;
    f32x4 hxL = *(const f32x4*)&PHx[iL];
    f32x4 hxH = *(const f32x4*)&PHx[iH];
    f32x4 htL = *(const f32x4*)&PHt[iL];
    f32x4 htH = *(const f32x4*)&PHt[iH];
    f32x4 oL, oH;
#pragma unroll
    for (int j = 0; j < 4; ++j) {
      // cur = fadd(fadd(xH,xT), fadd(tH,tT))  — proven R13 combine order
      oL[j] = __fadd_rn(__fadd_rn(hxL[j], xA[i][j]),
                        __fadd_rn(htL[j], tA[i][j]));
      oH[j] = __fadd_rn(__fadd_rn(hxH[j], xA[i][4 + j]),
                        __fadd_rn(htH[j], tA[i][4 + j]));
    }
    *(f32x4*)&PHx[iL] = oL;  // in-place: PHx becomes CUR
    *(f32x4*)&PHx[iH] = oH;
  }
}

// ---------------------------------------------------------------------------
// f32 LIF chain (np-exact): v = fl(fl(AL*v)+fl(BL*cur)); s=(v-1>0); reset.
// spikes {0,1}; rates = count/500.   [proven R13]
// ---------------------------------------------------------------------------
__global__ __launch_bounds__(256) void lif32(
    const float* __restrict__ CUR, float* __restrict__ spikes,
    float* __restrict__ rates) {
  const int j = blockIdx.x * 256 + threadIdx.x;  // b*512 + n
  const float AL = (float)AL64, BL = (float)BL64;
  float v = 0.0f;
  int cnt = 0;
#pragma unroll 10
  for (int t = 0; t < TSTEPS; ++t) {
    float cur = CUR[(size_t)t * SNEUR + j];
    v = __fadd_rn(__fmul_rn(AL, v), __fmul_rn(BL, cur));
    int sp = __fadd_rn(v, -1.0f) > 0.0f;
    cnt += sp;
    spikes[(size_t)t * SNEUR + j] = sp ? 1.0f : 0.0f;
    v = sp ? 0.0f : v;
  }
  rates[j] = __fdiv_rn((float)cnt, 500.0f);
}

extern "C" void kernel_launch(void* const* d_in, const int* in_sizes, int n_in,
                              void* d_out, int out_size, void* d_ws, size_t ws_size,
                              hipStream_t stream) {
  float* out = (float*)d_out;  // f32: spikes [500*64*512] ++ rates [64*512]

  float flag = 0.0f;
  const float* X = nullptr;
  const float* W = nullptr;
  const float* AP = nullptr;
  if (n_in != 3) {
    flag = 11.0f;
  } else {
    for (int i = 0; i < 3; ++i) {
      if (in_sizes[i] == 16384000) X = (const float*)d_in[i];
      else if (in_sizes[i] == 262144) W = (const float*)d_in[i];
      else if (in_sizes[i] == 1) AP = (const float*)d_in[i];
    }
    if (!X || !W || !AP) flag = 13.0f;
    else if (out_size != (int)OUTN) flag = 17.0f;
    else if (ws_size < WS_NEED) flag = 23.0f;
  }
  if (flag != 0.0f) {
    fill_const_f32<<<dim3(2048), dim3(256), 0, stream>>>(out, OUTN, flag);
    return;
  }

  char* ws = (char*)d_ws;
  float* TR = (float*)(ws);                    // trace    [32000,512] f32
  float* PHx = (float*)(ws + BUF_BYTES);       // x-head -> CUR (in-place)
  float* PHt = (float*)(ws + 2 * BUF_BYTES);   // trace-head partial

  trace32<<<dim3(NCH / 256), dim3(256), 0, stream>>>(X, TR, AP);
  gemm_head<<<dim3(2000), dim3(256), 0, stream>>>(X, TR, W, PHx, PHt);
  gemm_tail<<<dim3(2000), dim3(256), 0, stream>>>(X, TR, W, PHx, PHt);
  lif32<<<dim3(SNEUR / 256), dim3(256), 0, stream>>>(
      PHx, out, out + (size_t)TSTEPS * SNEUR);
}